// Round 7
// baseline (172.234 us; speedup 1.0000x reference)
//
#include <hip/hip_runtime.h>

#define D 128
#define BINCAP 6144
#define P2CAP 6144

typedef __attribute__((ext_vector_type(8))) short short8;
typedef __attribute__((ext_vector_type(4))) float f32x4;
typedef __attribute__((ext_vector_type(2))) float f32x2;

__device__ inline unsigned short f2bf(float f) {
    unsigned u = __float_as_uint(f);
    return (unsigned short)((u + 0x7FFFu + ((u >> 16) & 1u)) >> 16);
}

// ---------------------------------------------------------------- init (8 blocks): packW + cursors + pool + zero-rows
// P1 position->col: c(p) = (p&7)*16 + (p>>3).
__global__ __launch_bounds__(256) void k_initW(const float* __restrict__ w0, const float* __restrict__ w1,
                                               const float* __restrict__ b0, const float* __restrict__ b1,
                                               uint4* __restrict__ Wp0, uint4* __restrict__ Wp1,
                                               float* __restrict__ b0p, float* __restrict__ b1p,
                                               int* __restrict__ binCur, int* __restrict__ pool,
                                               uint2* __restrict__ rows0, float* __restrict__ scl0,
                                               unsigned* __restrict__ rows1, float* __restrict__ scl1,
                                               int nbins, int n) {
    int t = threadIdx.x, b = blockIdx.x;
    int e = b * 256 + t;                        // 2048 elements over 8 blocks
    {
        int l = e & 63, U = (e >> 6) & 7, T = e >> 9;
        int nn = U * 16 + (l & 15);
        int kq = T * 32 + ((l >> 4) << 3);
        unsigned r[4], s[4];
#pragma unroll
        for (int jj = 0; jj < 4; ++jj) {
            int k0 = kq + 2 * jj, k1 = k0 + 1;
            unsigned a0 = f2bf(w0[k0 * 128 + nn]), a1 = f2bf(w0[k1 * 128 + nn]);
            r[jj] = a0 | (a1 << 16);
            int c0 = ((k0 & 7) << 4) | (k0 >> 3), c1 = ((k1 & 7) << 4) | (k1 >> 3);
            unsigned q0 = f2bf(w1[c0 * 128 + nn]), q1 = f2bf(w1[c1 * 128 + nn]);
            s[jj] = q0 | (q1 << 16);
        }
        Wp0[e] = make_uint4(r[0], r[1], r[2], r[3]);
        Wp1[e] = make_uint4(s[0], s[1], s[2], s[3]);
    }
    if (b == 0) {
        if (t < nbins) binCur[t] = t * BINCAP;
        for (int i = t; i < 64 * 128; i += 256) pool[i] = 0;
    }
    if (b == 1 && t < 128) {
        int c = ((t & 7) << 4) | (t >> 3);
        b0p[t] = b0[c];
        b1p[t] = b1[c];
    }
    if (b == 2) {                               // zero rows at index n (gather padding target): s=0 -> contributes 0
        if (t < 16) rows0[(size_t)n * 16 + t] = make_uint2(0u, 0u);
        if (t < 16) rows1[(size_t)n * 16 + t] = 0u;
        if (t == 0) { scl0[n] = 0.f; scl1[n] = 0.f; }
    }
}

// ---------------------------------------------------------------- pass1 scatter into strided bins (LDS-grouped runs)
__global__ __launch_bounds__(256) void k_p1scatter(const int* __restrict__ row, const int* __restrict__ col,
                                                   int* __restrict__ binCur, unsigned* __restrict__ ebuf, int E) {
    __shared__ int h[256], delta[256], lcur[256], wt[4];
    __shared__ unsigned stage[4096];
    int t = threadIdx.x;
    int wv = t >> 6, l = t & 63;
    h[t] = 0;
    __syncthreads();
    int base = blockIdx.x * 4096;
    int cnt = min(4096, E - base);
    if (cnt == 4096) {
        int myc[16], myr[16];
        const int4* c4 = (const int4*)(col + base);
        const int4* r4 = (const int4*)(row + base);
#pragma unroll
        for (int k = 0; k < 4; ++k) {
            int4 cv = c4[t * 4 + k];
            int4 rv = r4[t * 4 + k];
            myc[k * 4 + 0] = cv.x; myc[k * 4 + 1] = cv.y; myc[k * 4 + 2] = cv.z; myc[k * 4 + 3] = cv.w;
            myr[k * 4 + 0] = rv.x; myr[k * 4 + 1] = rv.y; myr[k * 4 + 2] = rv.z; myr[k * 4 + 3] = rv.w;
        }
#pragma unroll
        for (int k = 0; k < 16; ++k) atomicAdd(&h[myc[k] >> 8], 1);
        __syncthreads();
        int v = h[t];
        int inc = v;
#pragma unroll
        for (int o = 1; o < 64; o <<= 1) {
            int x = __shfl_up(inc, o, 64);
            if (l >= o) inc += x;
        }
        if (l == 63) wt[wv] = inc;
        __syncthreads();
        int wbase = 0;
#pragma unroll
        for (int j = 0; j < 4; ++j) if (j < wv) wbase += wt[j];
        int excl = wbase + inc - v;
        lcur[t] = excl;
        delta[t] = (v > 0) ? (atomicAdd(&binCur[t], v) - excl) : 0;
        __syncthreads();
#pragma unroll
        for (int k = 0; k < 16; ++k) {
            int d = myc[k];
            int slot = atomicAdd(&lcur[d >> 8], 1);
            stage[slot] = ((unsigned)d << 16) | (unsigned)myr[k];   // n < 2^16: both fit
        }
        __syncthreads();
#pragma unroll
        for (int k = 0; k < 16; ++k) {
            int slot = k * 256 + t;
            unsigned vv = stage[slot];
            int b = vv >> 24;
            ebuf[delta[b] + slot] = vv;
        }
    } else {
        for (int k = 0; k < 16; ++k) {
            int e = base + k * 256 + t;
            if (e < E) atomicAdd(&h[col[e] >> 8], 1);
        }
        __syncthreads();
        int v = h[t];
        int inc = v;
#pragma unroll
        for (int o = 1; o < 64; o <<= 1) {
            int x = __shfl_up(inc, o, 64);
            if (l >= o) inc += x;
        }
        if (l == 63) wt[wv] = inc;
        __syncthreads();
        int wbase = 0;
#pragma unroll
        for (int j = 0; j < 4; ++j) if (j < wv) wbase += wt[j];
        int excl = wbase + inc - v;
        lcur[t] = excl;
        delta[t] = (v > 0) ? (atomicAdd(&binCur[t], v) - excl) : 0;
        __syncthreads();
        for (int k = 0; k < 16; ++k) {
            int e = base + k * 256 + t;
            if (e < E) {
                int d = col[e];
                int slot = atomicAdd(&lcur[d >> 8], 1);
                stage[slot] = ((unsigned)d << 16) | (unsigned)row[e];
            }
        }
        __syncthreads();
        for (int k = 0; k < 16; ++k) {
            int slot = k * 256 + t;
            if (slot < cnt) {
                unsigned vv = stage[slot];
                int b = vv >> 24;
                ebuf[delta[b] + slot] = vv;
            }
        }
    }
}

// ---------------------------------------------------------------- pass2: per-bin counting sort -> csr/off/end/dinv
__global__ __launch_bounds__(256) void k_p2sort(const unsigned* __restrict__ ebuf, const int* __restrict__ binCur,
                                                int* __restrict__ csr, int* __restrict__ off_, int* __restrict__ end_,
                                                float* __restrict__ dinv, int n) {
    __shared__ unsigned stage[P2CAP];
    __shared__ unsigned stage2[P2CAP];
    __shared__ int h[256], cur[256], wt[4];
    int b = blockIdx.x, t = threadIdx.x;
    int wv = t >> 6, l = t & 63;
    int beg = b * BINCAP;
    int cnt = binCur[b] - beg;
    h[t] = 0;
    __syncthreads();
    int nfull = cnt >> 2;
    const uint4* e4 = (const uint4*)(ebuf + beg);   // beg 16B aligned (BINCAP%4==0)
    uint4* st4 = (uint4*)stage;
    for (int i = t; i < nfull; i += 256) {
        uint4 v = e4[i];
        st4[i] = v;
        atomicAdd(&h[(v.x >> 16) & 0xFF], 1);
        atomicAdd(&h[(v.y >> 16) & 0xFF], 1);
        atomicAdd(&h[(v.z >> 16) & 0xFF], 1);
        atomicAdd(&h[(v.w >> 16) & 0xFF], 1);
    }
    for (int i = (nfull << 2) + t; i < cnt; i += 256) {
        unsigned v = ebuf[beg + i];
        stage[i] = v;
        atomicAdd(&h[(v >> 16) & 0xFF], 1);
    }
    __syncthreads();
    int v = h[t];
    int inc = v;
#pragma unroll
    for (int o = 1; o < 64; o <<= 1) {
        int x = __shfl_up(inc, o, 64);
        if (l >= o) inc += x;
    }
    if (l == 63) wt[wv] = inc;
    __syncthreads();
    int wbase = 0;
#pragma unroll
    for (int j = 0; j < 4; ++j) if (j < wv) wbase += wt[j];
    int excl = wbase + inc - v;
    cur[t] = excl;
    int d = b * 256 + t;
    if (d < n) {
        off_[d] = beg + excl;
        end_[d] = beg + excl + v;
        dinv[d] = rsqrtf((float)(v + 1));           // +1 self-loop
    }
    __syncthreads();
    for (int i = t; i < cnt; i += 256) {
        unsigned vv = stage[i];
        int slot = atomicAdd(&cur[(vv >> 16) & 0xFF], 1);
        stage2[slot] = vv & 0xFFFFu;
    }
    __syncthreads();
    uint4* c4o = (uint4*)(csr + beg);
    uint4* st24 = (uint4*)stage2;
    for (int i = t; i < nfull; i += 256) c4o[i] = st24[i];
    for (int i = (nfull << 2) + t; i < cnt; i += 256) csr[beg + i] = (int)stage2[i];
}

// ---------------------------------------------------------------- MFMA GEMM, fp32 input (conv0), out int8 per-row-scale rows
__global__ __launch_bounds__(256) void k_gemm0(const float* __restrict__ x, const uint4* __restrict__ Wp,
                                               const float* __restrict__ dinv,
                                               uint2* __restrict__ rows0, float* __restrict__ scl0, int n) {
    int wave = threadIdx.x >> 6, l = threadIdx.x & 63;
    int mt = blockIdx.x * 4 + wave;
    int r0 = mt * 16;
    if (r0 >= n) return;
    int rowA = r0 + (l & 15);
    int kq = (l >> 4) * 8;
    f32x4 acc[8];
#pragma unroll
    for (int U = 0; U < 8; ++U) acc[U] = (f32x4){0.f, 0.f, 0.f, 0.f};
    const float* xr = x + (size_t)rowA * 128 + kq;
#pragma unroll
    for (int T = 0; T < 4; ++T) {
        float4 a0 = *(const float4*)(xr + T * 32);
        float4 a1 = *(const float4*)(xr + T * 32 + 4);
        short8 af;
        af[0] = (short)f2bf(a0.x); af[1] = (short)f2bf(a0.y);
        af[2] = (short)f2bf(a0.z); af[3] = (short)f2bf(a0.w);
        af[4] = (short)f2bf(a1.x); af[5] = (short)f2bf(a1.y);
        af[6] = (short)f2bf(a1.z); af[7] = (short)f2bf(a1.w);
#pragma unroll
        for (int U = 0; U < 8; ++U) {
            short8 bf = *(const short8*)&Wp[(T * 8 + U) * 64 + l];
            acc[U] = __builtin_amdgcn_mfma_f32_16x16x32_bf16(af, bf, acc[U], 0, 0, 0);
        }
    }
    int rq = l >> 4, cl = l & 15;
#pragma unroll
    for (int qq = 0; qq < 4; ++qq) {
        int rr = r0 + rq * 4 + qq;
        float d = dinv[rr];
        float v[8];
        float am = 0.f;
#pragma unroll
        for (int U = 0; U < 8; ++U) { v[U] = acc[U][qq] * d; am = fmaxf(am, fabsf(v[U])); }
        am = fmaxf(am, __shfl_xor(am, 1, 64));
        am = fmaxf(am, __shfl_xor(am, 2, 64));
        am = fmaxf(am, __shfl_xor(am, 4, 64));
        am = fmaxf(am, __shfl_xor(am, 8, 64));
        float inv = (am > 0.f) ? 127.f / am : 0.f;
        unsigned bb[8];
#pragma unroll
        for (int U = 0; U < 8; ++U) bb[U] = (unsigned)(__float2int_rn(v[U] * inv) + 128);
        uint2 o;
        o.x = bb[0] | (bb[1] << 8) | (bb[2] << 16) | (bb[3] << 24);
        o.y = bb[4] | (bb[5] << 8) | (bb[6] << 16) | (bb[7] << 24);
        rows0[(size_t)rr * 16 + cl] = o;
        if (cl == 0) scl0[rr] = am * (1.f / 127.f);
    }
}

// ---------------------------------------------------------------- int8 gather core: wave = 4 nodes, 16 lanes/node
// 8-wide pipeline; row = 128B int8 + per-row scale s. value = (byte-128)*s; -128*s folded via ssum.
__device__ inline void gather8q(const uint2* __restrict__ rows, const float* __restrict__ scl,
                                const int* __restrict__ csr, int q, int beg, int len, int ZR,
                                f32x2 acc[4], float& ssum) {
    int maxlen = len;
    maxlen = max(maxlen, __shfl_xor(maxlen, 16, 64));
    maxlen = max(maxlen, __shfl_xor(maxlen, 32, 64));
    if (maxlen <= 0) return;
    int lm1 = len - 1;
    int s[8];
#pragma unroll
    for (int k = 0; k < 8; ++k) {
        int cv = csr[beg + min(k, lm1)];
        s[k] = (k < len) ? cv : ZR;
    }
    for (int j = 0; j < maxlen; j += 8) {
        uint2 u[8];
        float sc[8];
#pragma unroll
        for (int k = 0; k < 8; ++k) {
            u[k] = rows[(size_t)s[k] * 16 + q];
            sc[k] = scl[s[k]];
        }
        int jn = j + 8;
        if (jn < maxlen) {                      // wave-uniform branch
#pragma unroll
            for (int k = 0; k < 8; ++k) {
                int cv = csr[beg + min(jn + k, lm1)];
                s[k] = (jn + k < len) ? cv : ZR;
            }
        }
#pragma unroll
        for (int k = 0; k < 8; ++k) {
            float f = sc[k];
            unsigned vx = u[k].x, vy = u[k].y;
            acc[0][0] = fmaf((float)(vx & 0xFFu),         f, acc[0][0]);
            acc[0][1] = fmaf((float)((vx >> 8) & 0xFFu),  f, acc[0][1]);
            acc[1][0] = fmaf((float)((vx >> 16) & 0xFFu), f, acc[1][0]);
            acc[1][1] = fmaf((float)(vx >> 24),           f, acc[1][1]);
            acc[2][0] = fmaf((float)(vy & 0xFFu),         f, acc[2][0]);
            acc[2][1] = fmaf((float)((vy >> 8) & 0xFFu),  f, acc[2][1]);
            acc[3][0] = fmaf((float)((vy >> 16) & 0xFFu), f, acc[3][0]);
            acc[3][1] = fmaf((float)(vy >> 24),           f, acc[3][1]);
            ssum += f;
        }
    }
}

// ---------------------------------------------------------------- int4 gather core: wave = 4 nodes, 16 lanes/node
// row = 64B int4 (2 feat/byte) + per-row scale s. value = (nib-8)*s; -8*s folded via ssum.
__device__ inline void gather8q4(const unsigned* __restrict__ rows, const float* __restrict__ scl,
                                 const int* __restrict__ csr, int q, int beg, int len, int ZR,
                                 f32x2 acc[4], float& ssum) {
    int maxlen = len;
    maxlen = max(maxlen, __shfl_xor(maxlen, 16, 64));
    maxlen = max(maxlen, __shfl_xor(maxlen, 32, 64));
    if (maxlen <= 0) return;
    int lm1 = len - 1;
    int s[8];
#pragma unroll
    for (int k = 0; k < 8; ++k) {
        int cv = csr[beg + min(k, lm1)];
        s[k] = (k < len) ? cv : ZR;
    }
    for (int j = 0; j < maxlen; j += 8) {
        unsigned u[8];
        float sc[8];
#pragma unroll
        for (int k = 0; k < 8; ++k) {
            u[k] = rows[(size_t)s[k] * 16 + q];
            sc[k] = scl[s[k]];
        }
        int jn = j + 8;
        if (jn < maxlen) {                      // wave-uniform branch
#pragma unroll
            for (int k = 0; k < 8; ++k) {
                int cv = csr[beg + min(jn + k, lm1)];
                s[k] = (jn + k < len) ? cv : ZR;
            }
        }
#pragma unroll
        for (int k = 0; k < 8; ++k) {
            float f = sc[k];
            unsigned v = u[k];
            acc[0][0] = fmaf((float)(v & 0xFu),         f, acc[0][0]);
            acc[0][1] = fmaf((float)((v >> 4) & 0xFu),  f, acc[0][1]);
            acc[1][0] = fmaf((float)((v >> 8) & 0xFu),  f, acc[1][0]);
            acc[1][1] = fmaf((float)((v >> 12) & 0xFu), f, acc[1][1]);
            acc[2][0] = fmaf((float)((v >> 16) & 0xFu), f, acc[2][0]);
            acc[2][1] = fmaf((float)((v >> 20) & 0xFu), f, acc[2][1]);
            acc[3][0] = fmaf((float)((v >> 24) & 0xFu), f, acc[3][0]);
            acc[3][1] = fmaf((float)(v >> 28),          f, acc[3][1]);
            ssum += f;
        }
    }
}

// ---------------------------------------------------------------- fused agg(conv0) + GEMM(conv1), int8 in / int4 out
__global__ __launch_bounds__(256) void k_aggemm(const uint2* __restrict__ rows0, const float* __restrict__ scl0,
                                                const int* __restrict__ off_, const int* __restrict__ end_,
                                                const int* __restrict__ csr, const float* __restrict__ dinv,
                                                const float* __restrict__ bp, const uint4* __restrict__ Wp,
                                                unsigned* __restrict__ rows1, float* __restrict__ scl1, int n) {
    __shared__ uint4 sA[16 * 17];
    __shared__ float sM[4][16];
    __shared__ unsigned char sPB[16][64];
    int w = threadIdx.x >> 6, l = threadIdx.x & 63;
    int g = l >> 4, q = l & 15;
    int r0 = blockIdx.x * 16;
    int node = r0 + w * 4 + g;                  // n % 16 == 0
    f32x2 acc[4];
#pragma unroll
    for (int j = 0; j < 4; ++j) { acc[j][0] = 0.f; acc[j][1] = 0.f; }
    float ssum;
    {                                           // self-loop row
        uint2 us = rows0[(size_t)node * 16 + q];
        float f = scl0[node];
        unsigned vx = us.x, vy = us.y;
        acc[0][0] = fmaf((float)(vx & 0xFFu),         f, acc[0][0]);
        acc[0][1] = fmaf((float)((vx >> 8) & 0xFFu),  f, acc[0][1]);
        acc[1][0] = fmaf((float)((vx >> 16) & 0xFFu), f, acc[1][0]);
        acc[1][1] = fmaf((float)(vx >> 24),           f, acc[1][1]);
        acc[2][0] = fmaf((float)(vy & 0xFFu),         f, acc[2][0]);
        acc[2][1] = fmaf((float)((vy >> 8) & 0xFFu),  f, acc[2][1]);
        acc[3][0] = fmaf((float)((vy >> 16) & 0xFFu), f, acc[3][0]);
        acc[3][1] = fmaf((float)(vy >> 24),           f, acc[3][1]);
        ssum = f;
    }
    int beg = off_[node];
    int len = end_[node] - beg;
    gather8q(rows0, scl0, csr, q, beg, len, n, acc, ssum);
    float corr = -128.f * ssum;
    float d0 = dinv[node];
    const float4* bp4 = (const float4*)bp;
    float4 ba = bp4[q * 2], bb = bp4[q * 2 + 1];
    uint4 pk;
    pk.x = (unsigned)f2bf(fmaxf(fmaf(d0, acc[0][0] + corr, ba.x), 0.f)) | ((unsigned)f2bf(fmaxf(fmaf(d0, acc[0][1] + corr, ba.y), 0.f)) << 16);
    pk.y = (unsigned)f2bf(fmaxf(fmaf(d0, acc[1][0] + corr, ba.z), 0.f)) | ((unsigned)f2bf(fmaxf(fmaf(d0, acc[1][1] + corr, ba.w), 0.f)) << 16);
    pk.z = (unsigned)f2bf(fmaxf(fmaf(d0, acc[2][0] + corr, bb.x), 0.f)) | ((unsigned)f2bf(fmaxf(fmaf(d0, acc[2][1] + corr, bb.y), 0.f)) << 16);
    pk.w = (unsigned)f2bf(fmaxf(fmaf(d0, acc[3][0] + corr, bb.z), 0.f)) | ((unsigned)f2bf(fmaxf(fmaf(d0, acc[3][1] + corr, bb.w), 0.f)) << 16);
    sA[(w * 4 + g) * 17 + q] = pk;
    __syncthreads();
    int rq = l >> 4, cl = l & 15;
    f32x4 c0v = (f32x4){0.f, 0.f, 0.f, 0.f}, c1v = (f32x4){0.f, 0.f, 0.f, 0.f};
#pragma unroll
    for (int T = 0; T < 4; ++T) {
        short8 af = *(const short8*)&sA[(l & 15) * 17 + T * 4 + rq];
        short8 bf0 = *(const short8*)&Wp[(T * 8 + 2 * w) * 64 + l];
        short8 bf1 = *(const short8*)&Wp[(T * 8 + 2 * w + 1) * 64 + l];
        c0v = __builtin_amdgcn_mfma_f32_16x16x32_bf16(af, bf0, c0v, 0, 0, 0);
        c1v = __builtin_amdgcn_mfma_f32_16x16x32_bf16(af, bf1, c1v, 0, 0, 0);
    }
    // ---- int4 quantize 16 output rows (byte B=4*cl+w holds features 2B,2B+1 as low/high nibble)
    float cq0[4], cq1[4], am01[4];
#pragma unroll
    for (int qq = 0; qq < 4; ++qq) {
        int rr = r0 + rq * 4 + qq;
        float d2 = dinv[rr];
        cq0[qq] = c0v[qq] * d2;
        cq1[qq] = c1v[qq] * d2;
        float am = fmaxf(fabsf(cq0[qq]), fabsf(cq1[qq]));
        am = fmaxf(am, __shfl_xor(am, 1, 64));
        am = fmaxf(am, __shfl_xor(am, 2, 64));
        am = fmaxf(am, __shfl_xor(am, 4, 64));
        am = fmaxf(am, __shfl_xor(am, 8, 64));
        am01[qq] = am;
    }
    if (cl == 0) {
#pragma unroll
        for (int qq = 0; qq < 4; ++qq) sM[w][rq * 4 + qq] = am01[qq];
    }
    __syncthreads();
#pragma unroll
    for (int qq = 0; qq < 4; ++qq) {
        int rw = rq * 4 + qq;
        float m = fmaxf(fmaxf(sM[0][rw], sM[1][rw]), fmaxf(sM[2][rw], sM[3][rw]));
        float inv = (m > 0.f) ? 7.f / m : 0.f;
        unsigned q0 = (unsigned)(__float2int_rn(cq0[qq] * inv) + 8);
        unsigned q1 = (unsigned)(__float2int_rn(cq1[qq] * inv) + 8);
        sPB[rw][cl * 4 + w] = (unsigned char)(q0 | (q1 << 4));
        if (w == 0 && cl == 0) scl1[r0 + rw] = m * (1.f / 7.f);
    }
    __syncthreads();
    {
        int r = threadIdx.x >> 4, L = threadIdx.x & 15;
        unsigned o = (unsigned)sPB[r][4 * L + 0] | ((unsigned)sPB[r][4 * L + 1] << 8)
                   | ((unsigned)sPB[r][4 * L + 2] << 16) | ((unsigned)sPB[r][4 * L + 3] << 24);
        rows1[(size_t)(r0 + r) * 16 + L] = o;
    }
}

// ---------------------------------------------------------------- agg conv1 (int4 in) + fused segment-max pool
__global__ __launch_bounds__(256) void k_agg1(const unsigned* __restrict__ rows1, const float* __restrict__ scl1,
                                              const int* __restrict__ off_, const int* __restrict__ end_,
                                              const int* __restrict__ csr, const float* __restrict__ dinv,
                                              const float* __restrict__ bp, const int* __restrict__ batch,
                                              int* __restrict__ pool, int n) {
    __shared__ float2 sv[16][64];
    __shared__ int sg[16];
    int w = threadIdx.x >> 6, l = threadIdx.x & 63;
    int g = l >> 4, q = l & 15;
    int node = blockIdx.x * 16 + w * 4 + g;     // n % 16 == 0
    f32x2 acc[4];
#pragma unroll
    for (int j = 0; j < 4; ++j) { acc[j][0] = 0.f; acc[j][1] = 0.f; }
    float ssum;
    {                                           // self-loop row
        unsigned v = rows1[(size_t)node * 16 + q];
        float f = scl1[node];
        acc[0][0] = fmaf((float)(v & 0xFu),         f, acc[0][0]);
        acc[0][1] = fmaf((float)((v >> 4) & 0xFu),  f, acc[0][1]);
        acc[1][0] = fmaf((float)((v >> 8) & 0xFu),  f, acc[1][0]);
        acc[1][1] = fmaf((float)((v >> 12) & 0xFu), f, acc[1][1]);
        acc[2][0] = fmaf((float)((v >> 16) & 0xFu), f, acc[2][0]);
        acc[2][1] = fmaf((float)((v >> 20) & 0xFu), f, acc[2][1]);
        acc[3][0] = fmaf((float)((v >> 24) & 0xFu), f, acc[3][0]);
        acc[3][1] = fmaf((float)(v >> 28),          f, acc[3][1]);
        ssum = f;
    }
    int beg = off_[node];
    int len = end_[node] - beg;
    gather8q4(rows1, scl1, csr, q, beg, len, n, acc, ssum);
    float corr = -8.f * ssum;
    float d0 = dinv[node];
    const float4* bp4 = (const float4*)bp;
    float4 ba = bp4[q * 2], bb = bp4[q * 2 + 1];
    int rowi = w * 4 + g;
    sv[rowi][q * 4 + 0] = make_float2(fmaxf(fmaf(d0, acc[0][0] + corr, ba.x), 0.f), fmaxf(fmaf(d0, acc[0][1] + corr, ba.y), 0.f));
    sv[rowi][q * 4 + 1] = make_float2(fmaxf(fmaf(d0, acc[1][0] + corr, ba.z), 0.f), fmaxf(fmaf(d0, acc[1][1] + corr, ba.w), 0.f));
    sv[rowi][q * 4 + 2] = make_float2(fmaxf(fmaf(d0, acc[2][0] + corr, bb.x), 0.f), fmaxf(fmaf(d0, acc[2][1] + corr, bb.y), 0.f));
    sv[rowi][q * 4 + 3] = make_float2(fmaxf(fmaf(d0, acc[3][0] + corr, bb.z), 0.f), fmaxf(fmaf(d0, acc[3][1] + corr, bb.w), 0.f));
    if (q == 0) sg[rowi] = batch[node];
    __syncthreads();
    if (threadIdx.x < 64) {
        int t = threadIdx.x;
        int c0 = 32 * (t & 3) + (t >> 2);       // true col of position 2t; pair col = c0+16
        int cur = sg[0];
        float2 m = sv[0][t];
        for (int ww = 1; ww < 16; ++ww) {
            int gg = sg[ww];
            float2 vv = sv[ww][t];
            if (gg == cur) { m.x = fmaxf(m.x, vv.x); m.y = fmaxf(m.y, vv.y); }
            else {
                atomicMax(&pool[cur * 128 + c0], __float_as_int(m.x));
                atomicMax(&pool[cur * 128 + c0 + 16], __float_as_int(m.y));
                cur = gg; m = vv;
            }
        }
        atomicMax(&pool[cur * 128 + c0], __float_as_int(m.x));
        atomicMax(&pool[cur * 128 + c0 + 16], __float_as_int(m.y));
    }
}

// ---------------------------------------------------------------- final MLP + log_softmax, 1 block/graph
__global__ __launch_bounds__(128) void k_mlp(const float* __restrict__ pool, const float* __restrict__ W0,
                                             const float* __restrict__ b0, const float* __restrict__ W1,
                                             const float* __restrict__ b1, float* __restrict__ out) {
    __shared__ float rowv[128];
    __shared__ float h2[128];
    __shared__ float ps[80];
    __shared__ float h3[10];
    __shared__ float lsed;
    int g = blockIdx.x, t = threadIdx.x;
    rowv[t] = pool[g * 128 + t];
    __syncthreads();
    float acc = b0[t];
    for (int k = 0; k < 128; ++k) acc = fmaf(rowv[k], W0[k * 128 + t], acc);
    h2[t] = fmaxf(acc, 0.f);
    __syncthreads();
    if (t < 80) {                               // layer 2: 10 outputs x 8 partials
        int j = t >> 3, p = t & 7;
        float a = 0.f;
        int k0 = p * 16;
        for (int k = k0; k < k0 + 16; ++k) a = fmaf(h2[k], W1[k * 10 + j], a);
        ps[t] = a;
    }
    __syncthreads();
    if (t < 10) {
        float a = b1[t];
#pragma unroll
        for (int p = 0; p < 8; ++p) a += ps[t * 8 + p];
        h3[t] = fmaxf(a, 0.f);
    }
    __syncthreads();
    if (t == 0) {
        float mx = h3[0];
        for (int j = 1; j < 10; ++j) mx = fmaxf(mx, h3[j]);
        float s = 0.f;
        for (int j = 0; j < 10; ++j) s += expf(h3[j] - mx);
        lsed = logf(s) + mx;
    }
    __syncthreads();
    if (t < 10) out[g * 10 + t] = h3[t] - lsed;
}

// ----------------------------------------------------------------
extern "C" void kernel_launch(void* const* d_in, const int* in_sizes, int n_in,
                              void* d_out, int out_size, void* d_ws, size_t ws_size,
                              hipStream_t stream) {
    const float* x   = (const float*)d_in[0];
    const int* eidx  = (const int*)d_in[1];
    const int* batch = (const int*)d_in[2];
    const float* w0  = (const float*)d_in[3];
    const float* b0  = (const float*)d_in[4];
    const float* w1  = (const float*)d_in[5];
    const float* b1  = (const float*)d_in[6];
    const float* lw0 = (const float*)d_in[7];
    const float* lb0 = (const float*)d_in[8];
    const float* lw1 = (const float*)d_in[9];
    const float* lb1 = (const float*)d_in[10];
    float* out = (float*)d_out;

    int n = in_sizes[2];
    int E = in_sizes[1] / 2;
    const int* row = eidx;        // sources
    const int* col = eidx + E;    // destinations
    int nbins = (n + 255) >> 8;   // 196 (n < 2^16 required for packing)
    int nb1 = (E + 4095) / 4096;

    char* ws = (char*)d_ws;
    size_t o = 0;
    auto take = [&](size_t bytes) { void* p = ws + o; o += (bytes + 255) & ~(size_t)255; return p; };
    int*      binCur   = (int*)     take(256 * 4);
    int*      off_     = (int*)     take((size_t)n * 4);
    int*      end_     = (int*)     take((size_t)n * 4);
    float*    dinv     = (float*)   take((size_t)n * 4);
    int*      csrA     = (int*)     take(((size_t)nbins * BINCAP + 128) * 4);
    int*      csr      = csrA + 64;                                  // 64-slot front pad
    unsigned* ebuf     = (unsigned*)take(((size_t)nbins * BINCAP + 64) * 4);
    uint4*    Wp0      = (uint4*)   take(2048 * 16);
    uint4*    Wp1      = (uint4*)   take(2048 * 16);
    float*    b0p      = (float*)   take(128 * 4);
    float*    b1p      = (float*)   take(128 * 4);
    uint2*    rows0    = (uint2*)   take((size_t)(n + 1) * 128);     // int8 rows + zero row
    float*    scl0     = (float*)   take((size_t)(n + 1) * 4);
    unsigned* rows1    = (unsigned*)take((size_t)(n + 1) * 64);      // int4 rows + zero row
    float*    scl1     = (float*)   take((size_t)(n + 1) * 4);
    int*      pool     = (int*)     take(64 * 128 * 4);

    k_initW<<<8, 256, 0, stream>>>(w0, w1, b0, b1, Wp0, Wp1, b0p, b1p, binCur, pool,
                                   rows0, scl0, rows1, scl1, nbins, n);
    k_p1scatter<<<nb1, 256, 0, stream>>>(row, col, binCur, ebuf, E);
    k_p2sort<<<nbins, 256, 0, stream>>>(ebuf, binCur, csr, off_, end_, dinv, n);

    int mtBlocks = ((n + 15) / 16 + 3) / 4;

    k_gemm0<<<mtBlocks, 256, 0, stream>>>(x, Wp0, dinv, rows0, scl0, n);
    k_aggemm<<<n / 16, 256, 0, stream>>>(rows0, scl0, off_, end_, csr, dinv, b0p, Wp1, rows1, scl1, n);
    k_agg1<<<n / 16, 256, 0, stream>>>(rows1, scl1, off_, end_, csr, dinv, b1p, batch, pool, n);
    k_mlp<<<64, 128, 0, stream>>>((const float*)pool, lw0, lb0, lw1, lb1, out);
}

// Round 8
// 168.218 us; speedup vs baseline: 1.0239x; 1.0239x over previous
//
#include <hip/hip_runtime.h>

#define D 128
#define BINCAP 6144
#define P2CAP 6144

typedef __attribute__((ext_vector_type(8))) short short8;
typedef __attribute__((ext_vector_type(4))) float f32x4;
typedef __attribute__((ext_vector_type(2))) float f32x2;

__device__ inline unsigned short f2bf(float f) {
    unsigned u = __float_as_uint(f);
    return (unsigned short)((u + 0x7FFFu + ((u >> 16) & 1u)) >> 16);
}

// ---------------------------------------------------------------- init (8 blocks): packW + cursors + pool + zero-rows
// P1 position->col: c(p) = (p&7)*16 + (p>>3).
__global__ __launch_bounds__(256) void k_initW(const float* __restrict__ w0, const float* __restrict__ w1,
                                               const float* __restrict__ b0, const float* __restrict__ b1,
                                               uint4* __restrict__ Wp0, uint4* __restrict__ Wp1,
                                               float* __restrict__ b0p, float* __restrict__ b1p,
                                               int* __restrict__ binCur, int* __restrict__ pool,
                                               uint2* __restrict__ rows0, float* __restrict__ scl0,
                                               uint2* __restrict__ rows1, float* __restrict__ scl1,
                                               int nbins, int n) {
    int t = threadIdx.x, b = blockIdx.x;
    int e = b * 256 + t;                        // 2048 elements over 8 blocks
    {
        int l = e & 63, U = (e >> 6) & 7, T = e >> 9;
        int nn = U * 16 + (l & 15);
        int kq = T * 32 + ((l >> 4) << 3);
        unsigned r[4], s[4];
#pragma unroll
        for (int jj = 0; jj < 4; ++jj) {
            int k0 = kq + 2 * jj, k1 = k0 + 1;
            unsigned a0 = f2bf(w0[k0 * 128 + nn]), a1 = f2bf(w0[k1 * 128 + nn]);
            r[jj] = a0 | (a1 << 16);
            int c0 = ((k0 & 7) << 4) | (k0 >> 3), c1 = ((k1 & 7) << 4) | (k1 >> 3);
            unsigned q0 = f2bf(w1[c0 * 128 + nn]), q1 = f2bf(w1[c1 * 128 + nn]);
            s[jj] = q0 | (q1 << 16);
        }
        Wp0[e] = make_uint4(r[0], r[1], r[2], r[3]);
        Wp1[e] = make_uint4(s[0], s[1], s[2], s[3]);
    }
    if (b == 0) {
        if (t < nbins) binCur[t] = t * BINCAP;
        for (int i = t; i < 64 * 128; i += 256) pool[i] = 0;
    }
    if (b == 1 && t < 128) {
        int c = ((t & 7) << 4) | (t >> 3);
        b0p[t] = b0[c];
        b1p[t] = b1[c];
    }
    if (b == 2) {                               // zero row at index n (gather padding target): s=0 -> contributes 0
        if (t < 16) rows0[(size_t)n * 16 + t] = make_uint2(0u, 0u);
        if (t < 16) rows1[(size_t)n * 16 + t] = make_uint2(0u, 0u);
        if (t == 0) { scl0[n] = 0.f; scl1[n] = 0.f; }
    }
}

// ---------------------------------------------------------------- pass1 scatter into strided bins (LDS-grouped runs)
__global__ __launch_bounds__(256) void k_p1scatter(const int* __restrict__ row, const int* __restrict__ col,
                                                   int* __restrict__ binCur, unsigned* __restrict__ ebuf, int E) {
    __shared__ int h[256], delta[256], lcur[256], wt[4];
    __shared__ unsigned stage[4096];
    int t = threadIdx.x;
    int wv = t >> 6, l = t & 63;
    h[t] = 0;
    __syncthreads();
    int base = blockIdx.x * 4096;
    int cnt = min(4096, E - base);
    if (cnt == 4096) {
        int myc[16], myr[16];
        const int4* c4 = (const int4*)(col + base);
        const int4* r4 = (const int4*)(row + base);
#pragma unroll
        for (int k = 0; k < 4; ++k) {
            int4 cv = c4[t * 4 + k];
            int4 rv = r4[t * 4 + k];
            myc[k * 4 + 0] = cv.x; myc[k * 4 + 1] = cv.y; myc[k * 4 + 2] = cv.z; myc[k * 4 + 3] = cv.w;
            myr[k * 4 + 0] = rv.x; myr[k * 4 + 1] = rv.y; myr[k * 4 + 2] = rv.z; myr[k * 4 + 3] = rv.w;
        }
#pragma unroll
        for (int k = 0; k < 16; ++k) atomicAdd(&h[myc[k] >> 8], 1);
        __syncthreads();
        int v = h[t];
        int inc = v;
#pragma unroll
        for (int o = 1; o < 64; o <<= 1) {
            int x = __shfl_up(inc, o, 64);
            if (l >= o) inc += x;
        }
        if (l == 63) wt[wv] = inc;
        __syncthreads();
        int wbase = 0;
#pragma unroll
        for (int j = 0; j < 4; ++j) if (j < wv) wbase += wt[j];
        int excl = wbase + inc - v;
        lcur[t] = excl;
        delta[t] = (v > 0) ? (atomicAdd(&binCur[t], v) - excl) : 0;
        __syncthreads();
#pragma unroll
        for (int k = 0; k < 16; ++k) {
            int d = myc[k];
            int slot = atomicAdd(&lcur[d >> 8], 1);
            stage[slot] = ((unsigned)d << 16) | (unsigned)myr[k];   // n < 2^16: both fit
        }
        __syncthreads();
#pragma unroll
        for (int k = 0; k < 16; ++k) {
            int slot = k * 256 + t;
            unsigned vv = stage[slot];
            int b = vv >> 24;
            ebuf[delta[b] + slot] = vv;
        }
    } else {
        for (int k = 0; k < 16; ++k) {
            int e = base + k * 256 + t;
            if (e < E) atomicAdd(&h[col[e] >> 8], 1);
        }
        __syncthreads();
        int v = h[t];
        int inc = v;
#pragma unroll
        for (int o = 1; o < 64; o <<= 1) {
            int x = __shfl_up(inc, o, 64);
            if (l >= o) inc += x;
        }
        if (l == 63) wt[wv] = inc;
        __syncthreads();
        int wbase = 0;
#pragma unroll
        for (int j = 0; j < 4; ++j) if (j < wv) wbase += wt[j];
        int excl = wbase + inc - v;
        lcur[t] = excl;
        delta[t] = (v > 0) ? (atomicAdd(&binCur[t], v) - excl) : 0;
        __syncthreads();
        for (int k = 0; k < 16; ++k) {
            int e = base + k * 256 + t;
            if (e < E) {
                int d = col[e];
                int slot = atomicAdd(&lcur[d >> 8], 1);
                stage[slot] = ((unsigned)d << 16) | (unsigned)row[e];
            }
        }
        __syncthreads();
        for (int k = 0; k < 16; ++k) {
            int slot = k * 256 + t;
            if (slot < cnt) {
                unsigned vv = stage[slot];
                int b = vv >> 24;
                ebuf[delta[b] + slot] = vv;
            }
        }
    }
}

// ---------------------------------------------------------------- pass2: per-bin counting sort -> csr/off/end/dinv
__global__ __launch_bounds__(256) void k_p2sort(const unsigned* __restrict__ ebuf, const int* __restrict__ binCur,
                                                int* __restrict__ csr, int* __restrict__ off_, int* __restrict__ end_,
                                                float* __restrict__ dinv, int n) {
    __shared__ unsigned stage[P2CAP];
    __shared__ unsigned stage2[P2CAP];
    __shared__ int h[256], cur[256], wt[4];
    int b = blockIdx.x, t = threadIdx.x;
    int wv = t >> 6, l = t & 63;
    int beg = b * BINCAP;
    int cnt = binCur[b] - beg;
    h[t] = 0;
    __syncthreads();
    int nfull = cnt >> 2;
    const uint4* e4 = (const uint4*)(ebuf + beg);   // beg 16B aligned (BINCAP%4==0)
    uint4* st4 = (uint4*)stage;
    for (int i = t; i < nfull; i += 256) {
        uint4 v = e4[i];
        st4[i] = v;
        atomicAdd(&h[(v.x >> 16) & 0xFF], 1);
        atomicAdd(&h[(v.y >> 16) & 0xFF], 1);
        atomicAdd(&h[(v.z >> 16) & 0xFF], 1);
        atomicAdd(&h[(v.w >> 16) & 0xFF], 1);
    }
    for (int i = (nfull << 2) + t; i < cnt; i += 256) {
        unsigned v = ebuf[beg + i];
        stage[i] = v;
        atomicAdd(&h[(v >> 16) & 0xFF], 1);
    }
    __syncthreads();
    int v = h[t];
    int inc = v;
#pragma unroll
    for (int o = 1; o < 64; o <<= 1) {
        int x = __shfl_up(inc, o, 64);
        if (l >= o) inc += x;
    }
    if (l == 63) wt[wv] = inc;
    __syncthreads();
    int wbase = 0;
#pragma unroll
    for (int j = 0; j < 4; ++j) if (j < wv) wbase += wt[j];
    int excl = wbase + inc - v;
    cur[t] = excl;
    int d = b * 256 + t;
    if (d < n) {
        off_[d] = beg + excl;
        end_[d] = beg + excl + v;
        dinv[d] = rsqrtf((float)(v + 1));           // +1 self-loop
    }
    __syncthreads();
    for (int i = t; i < cnt; i += 256) {
        unsigned vv = stage[i];
        int slot = atomicAdd(&cur[(vv >> 16) & 0xFF], 1);
        stage2[slot] = vv & 0xFFFFu;
    }
    __syncthreads();
    uint4* c4o = (uint4*)(csr + beg);
    uint4* st24 = (uint4*)stage2;
    for (int i = t; i < nfull; i += 256) c4o[i] = st24[i];
    for (int i = (nfull << 2) + t; i < cnt; i += 256) csr[beg + i] = (int)stage2[i];
}

// ---------------------------------------------------------------- MFMA GEMM, fp32 input (conv0), out int8 per-row-scale rows
__global__ __launch_bounds__(256) void k_gemm0(const float* __restrict__ x, const uint4* __restrict__ Wp,
                                               const float* __restrict__ dinv,
                                               uint2* __restrict__ rows0, float* __restrict__ scl0, int n) {
    int wave = threadIdx.x >> 6, l = threadIdx.x & 63;
    int mt = blockIdx.x * 4 + wave;
    int r0 = mt * 16;
    if (r0 >= n) return;
    int rowA = r0 + (l & 15);
    int kq = (l >> 4) * 8;
    f32x4 acc[8];
#pragma unroll
    for (int U = 0; U < 8; ++U) acc[U] = (f32x4){0.f, 0.f, 0.f, 0.f};
    const float* xr = x + (size_t)rowA * 128 + kq;
#pragma unroll
    for (int T = 0; T < 4; ++T) {
        float4 a0 = *(const float4*)(xr + T * 32);
        float4 a1 = *(const float4*)(xr + T * 32 + 4);
        short8 af;
        af[0] = (short)f2bf(a0.x); af[1] = (short)f2bf(a0.y);
        af[2] = (short)f2bf(a0.z); af[3] = (short)f2bf(a0.w);
        af[4] = (short)f2bf(a1.x); af[5] = (short)f2bf(a1.y);
        af[6] = (short)f2bf(a1.z); af[7] = (short)f2bf(a1.w);
#pragma unroll
        for (int U = 0; U < 8; ++U) {
            short8 bf = *(const short8*)&Wp[(T * 8 + U) * 64 + l];
            acc[U] = __builtin_amdgcn_mfma_f32_16x16x32_bf16(af, bf, acc[U], 0, 0, 0);
        }
    }
    int rq = l >> 4, cl = l & 15;
#pragma unroll
    for (int qq = 0; qq < 4; ++qq) {
        int rr = r0 + rq * 4 + qq;
        float d = dinv[rr];
        float v[8];
        float am = 0.f;
#pragma unroll
        for (int U = 0; U < 8; ++U) { v[U] = acc[U][qq] * d; am = fmaxf(am, fabsf(v[U])); }
        am = fmaxf(am, __shfl_xor(am, 1, 64));
        am = fmaxf(am, __shfl_xor(am, 2, 64));
        am = fmaxf(am, __shfl_xor(am, 4, 64));
        am = fmaxf(am, __shfl_xor(am, 8, 64));
        float inv = (am > 0.f) ? 127.f / am : 0.f;
        unsigned bb[8];
#pragma unroll
        for (int U = 0; U < 8; ++U) bb[U] = (unsigned)(__float2int_rn(v[U] * inv) + 128);
        uint2 o;
        o.x = bb[0] | (bb[1] << 8) | (bb[2] << 16) | (bb[3] << 24);
        o.y = bb[4] | (bb[5] << 8) | (bb[6] << 16) | (bb[7] << 24);
        rows0[(size_t)rr * 16 + cl] = o;
        if (cl == 0) scl0[rr] = am * (1.f / 127.f);
    }
}

// ---------------------------------------------------------------- int8 gather core: wave = 4 nodes, 16 lanes/node
// 8-wide pipeline; row = 128B int8 + per-row scale s. value = (byte-128)*s; the -128*s constant is
// accumulated as one scalar (ssum) and applied once at the end. Out-of-range slots -> ZR (s=0 row).
__device__ inline void gather8q(const uint2* __restrict__ rows, const float* __restrict__ scl,
                                const int* __restrict__ csr, int q, int beg, int len, int ZR,
                                f32x2 acc[4], float& ssum) {
    int maxlen = len;
    maxlen = max(maxlen, __shfl_xor(maxlen, 16, 64));
    maxlen = max(maxlen, __shfl_xor(maxlen, 32, 64));
    if (maxlen <= 0) return;
    int lm1 = len - 1;
    int s[8];
#pragma unroll
    for (int k = 0; k < 8; ++k) {
        int cv = csr[beg + min(k, lm1)];
        s[k] = (k < len) ? cv : ZR;
    }
    for (int j = 0; j < maxlen; j += 8) {
        uint2 u[8];
        float sc[8];
#pragma unroll
        for (int k = 0; k < 8; ++k) {
            u[k] = rows[(size_t)s[k] * 16 + q];
            sc[k] = scl[s[k]];
        }
        int jn = j + 8;
        if (jn < maxlen) {                      // wave-uniform branch
#pragma unroll
            for (int k = 0; k < 8; ++k) {
                int cv = csr[beg + min(jn + k, lm1)];
                s[k] = (jn + k < len) ? cv : ZR;
            }
        }
#pragma unroll
        for (int k = 0; k < 8; ++k) {
            float f = sc[k];
            unsigned vx = u[k].x, vy = u[k].y;
            acc[0][0] = fmaf((float)(vx & 0xFFu),         f, acc[0][0]);
            acc[0][1] = fmaf((float)((vx >> 8) & 0xFFu),  f, acc[0][1]);
            acc[1][0] = fmaf((float)((vx >> 16) & 0xFFu), f, acc[1][0]);
            acc[1][1] = fmaf((float)(vx >> 24),           f, acc[1][1]);
            acc[2][0] = fmaf((float)(vy & 0xFFu),         f, acc[2][0]);
            acc[2][1] = fmaf((float)((vy >> 8) & 0xFFu),  f, acc[2][1]);
            acc[3][0] = fmaf((float)((vy >> 16) & 0xFFu), f, acc[3][0]);
            acc[3][1] = fmaf((float)(vy >> 24),           f, acc[3][1]);
            ssum += f;
        }
    }
}

// ---------------------------------------------------------------- fused agg(conv0) + GEMM(conv1), int8 in / int8 out
__global__ __launch_bounds__(256) void k_aggemm(const uint2* __restrict__ rows0, const float* __restrict__ scl0,
                                                const int* __restrict__ off_, const int* __restrict__ end_,
                                                const int* __restrict__ csr, const float* __restrict__ dinv,
                                                const float* __restrict__ bp, const uint4* __restrict__ Wp,
                                                uint2* __restrict__ rows1, float* __restrict__ scl1, int n) {
    __shared__ uint4 sA[16 * 17];
    __shared__ float sM[4][16];
    __shared__ unsigned short sPB[16][64];
    int w = threadIdx.x >> 6, l = threadIdx.x & 63;
    int g = l >> 4, q = l & 15;
    int r0 = blockIdx.x * 16;
    int node = r0 + w * 4 + g;                  // n % 16 == 0
    f32x2 acc[4];
#pragma unroll
    for (int j = 0; j < 4; ++j) { acc[j][0] = 0.f; acc[j][1] = 0.f; }
    float ssum;
    {                                           // self-loop row
        uint2 us = rows0[(size_t)node * 16 + q];
        float f = scl0[node];
        unsigned vx = us.x, vy = us.y;
        acc[0][0] = fmaf((float)(vx & 0xFFu),         f, acc[0][0]);
        acc[0][1] = fmaf((float)((vx >> 8) & 0xFFu),  f, acc[0][1]);
        acc[1][0] = fmaf((float)((vx >> 16) & 0xFFu), f, acc[1][0]);
        acc[1][1] = fmaf((float)(vx >> 24),           f, acc[1][1]);
        acc[2][0] = fmaf((float)(vy & 0xFFu),         f, acc[2][0]);
        acc[2][1] = fmaf((float)((vy >> 8) & 0xFFu),  f, acc[2][1]);
        acc[3][0] = fmaf((float)((vy >> 16) & 0xFFu), f, acc[3][0]);
        acc[3][1] = fmaf((float)(vy >> 24),           f, acc[3][1]);
        ssum = f;
    }
    int beg = off_[node];
    int len = end_[node] - beg;
    gather8q(rows0, scl0, csr, q, beg, len, n, acc, ssum);
    float corr = -128.f * ssum;
    float d0 = dinv[node];
    const float4* bp4 = (const float4*)bp;
    float4 ba = bp4[q * 2], bb = bp4[q * 2 + 1];
    uint4 pk;
    pk.x = (unsigned)f2bf(fmaxf(fmaf(d0, acc[0][0] + corr, ba.x), 0.f)) | ((unsigned)f2bf(fmaxf(fmaf(d0, acc[0][1] + corr, ba.y), 0.f)) << 16);
    pk.y = (unsigned)f2bf(fmaxf(fmaf(d0, acc[1][0] + corr, ba.z), 0.f)) | ((unsigned)f2bf(fmaxf(fmaf(d0, acc[1][1] + corr, ba.w), 0.f)) << 16);
    pk.z = (unsigned)f2bf(fmaxf(fmaf(d0, acc[2][0] + corr, bb.x), 0.f)) | ((unsigned)f2bf(fmaxf(fmaf(d0, acc[2][1] + corr, bb.y), 0.f)) << 16);
    pk.w = (unsigned)f2bf(fmaxf(fmaf(d0, acc[3][0] + corr, bb.z), 0.f)) | ((unsigned)f2bf(fmaxf(fmaf(d0, acc[3][1] + corr, bb.w), 0.f)) << 16);
    sA[(w * 4 + g) * 17 + q] = pk;
    __syncthreads();
    int rq = l >> 4, cl = l & 15;
    f32x4 c0v = (f32x4){0.f, 0.f, 0.f, 0.f}, c1v = (f32x4){0.f, 0.f, 0.f, 0.f};
#pragma unroll
    for (int T = 0; T < 4; ++T) {
        short8 af = *(const short8*)&sA[(l & 15) * 17 + T * 4 + rq];
        short8 bf0 = *(const short8*)&Wp[(T * 8 + 2 * w) * 64 + l];
        short8 bf1 = *(const short8*)&Wp[(T * 8 + 2 * w + 1) * 64 + l];
        c0v = __builtin_amdgcn_mfma_f32_16x16x32_bf16(af, bf0, c0v, 0, 0, 0);
        c1v = __builtin_amdgcn_mfma_f32_16x16x32_bf16(af, bf1, c1v, 0, 0, 0);
    }
    // ---- int8 quantize 16 output rows (feature p = 8*cl + 2*w + e, e=0:c0v e=1:c1v)
    float cq0[4], cq1[4], am01[4];
#pragma unroll
    for (int qq = 0; qq < 4; ++qq) {
        int rr = r0 + rq * 4 + qq;
        float d2 = dinv[rr];
        cq0[qq] = c0v[qq] * d2;
        cq1[qq] = c1v[qq] * d2;
        float am = fmaxf(fabsf(cq0[qq]), fabsf(cq1[qq]));
        am = fmaxf(am, __shfl_xor(am, 1, 64));
        am = fmaxf(am, __shfl_xor(am, 2, 64));
        am = fmaxf(am, __shfl_xor(am, 4, 64));
        am = fmaxf(am, __shfl_xor(am, 8, 64));
        am01[qq] = am;
    }
    if (cl == 0) {
#pragma unroll
        for (int qq = 0; qq < 4; ++qq) sM[w][rq * 4 + qq] = am01[qq];
    }
    __syncthreads();
#pragma unroll
    for (int qq = 0; qq < 4; ++qq) {
        int rw = rq * 4 + qq;
        float m = fmaxf(fmaxf(sM[0][rw], sM[1][rw]), fmaxf(sM[2][rw], sM[3][rw]));
        float inv = (m > 0.f) ? 127.f / m : 0.f;
        unsigned q0 = (unsigned)(__float2int_rn(cq0[qq] * inv) + 128);
        unsigned q1 = (unsigned)(__float2int_rn(cq1[qq] * inv) + 128);
        sPB[rw][cl * 4 + w] = (unsigned short)(q0 | (q1 << 8));
        if (w == 0 && cl == 0) scl1[r0 + rw] = m * (1.f / 127.f);
    }
    __syncthreads();
    {
        int r = threadIdx.x >> 4, L = threadIdx.x & 15;
        uint2 o;
        o.x = (unsigned)sPB[r][4 * L + 0] | ((unsigned)sPB[r][4 * L + 1] << 16);
        o.y = (unsigned)sPB[r][4 * L + 2] | ((unsigned)sPB[r][4 * L + 3] << 16);
        rows1[(size_t)(r0 + r) * 16 + L] = o;
    }
}

// ---------------------------------------------------------------- agg conv1 (int8 in) + fused segment-max pool
__global__ __launch_bounds__(256) void k_agg1(const uint2* __restrict__ rows1, const float* __restrict__ scl1,
                                              const int* __restrict__ off_, const int* __restrict__ end_,
                                              const int* __restrict__ csr, const float* __restrict__ dinv,
                                              const float* __restrict__ bp, const int* __restrict__ batch,
                                              int* __restrict__ pool, int n) {
    __shared__ float2 sv[16][64];
    __shared__ int sg[16];
    int w = threadIdx.x >> 6, l = threadIdx.x & 63;
    int g = l >> 4, q = l & 15;
    int node = blockIdx.x * 16 + w * 4 + g;     // n % 16 == 0
    f32x2 acc[4];
#pragma unroll
    for (int j = 0; j < 4; ++j) { acc[j][0] = 0.f; acc[j][1] = 0.f; }
    float ssum;
    {                                           // self-loop row
        uint2 us = rows1[(size_t)node * 16 + q];
        float f = scl1[node];
        unsigned vx = us.x, vy = us.y;
        acc[0][0] = fmaf((float)(vx & 0xFFu),         f, acc[0][0]);
        acc[0][1] = fmaf((float)((vx >> 8) & 0xFFu),  f, acc[0][1]);
        acc[1][0] = fmaf((float)((vx >> 16) & 0xFFu), f, acc[1][0]);
        acc[1][1] = fmaf((float)(vx >> 24),           f, acc[1][1]);
        acc[2][0] = fmaf((float)(vy & 0xFFu),         f, acc[2][0]);
        acc[2][1] = fmaf((float)((vy >> 8) & 0xFFu),  f, acc[2][1]);
        acc[3][0] = fmaf((float)((vy >> 16) & 0xFFu), f, acc[3][0]);
        acc[3][1] = fmaf((float)(vy >> 24),           f, acc[3][1]);
        ssum = f;
    }
    int beg = off_[node];
    int len = end_[node] - beg;
    gather8q(rows1, scl1, csr, q, beg, len, n, acc, ssum);
    float corr = -128.f * ssum;
    float d0 = dinv[node];
    const float4* bp4 = (const float4*)bp;
    float4 ba = bp4[q * 2], bb = bp4[q * 2 + 1];
    int rowi = w * 4 + g;
    sv[rowi][q * 4 + 0] = make_float2(fmaxf(fmaf(d0, acc[0][0] + corr, ba.x), 0.f), fmaxf(fmaf(d0, acc[0][1] + corr, ba.y), 0.f));
    sv[rowi][q * 4 + 1] = make_float2(fmaxf(fmaf(d0, acc[1][0] + corr, ba.z), 0.f), fmaxf(fmaf(d0, acc[1][1] + corr, ba.w), 0.f));
    sv[rowi][q * 4 + 2] = make_float2(fmaxf(fmaf(d0, acc[2][0] + corr, bb.x), 0.f), fmaxf(fmaf(d0, acc[2][1] + corr, bb.y), 0.f));
    sv[rowi][q * 4 + 3] = make_float2(fmaxf(fmaf(d0, acc[3][0] + corr, bb.z), 0.f), fmaxf(fmaf(d0, acc[3][1] + corr, bb.w), 0.f));
    if (q == 0) sg[rowi] = batch[node];
    __syncthreads();
    if (threadIdx.x < 64) {
        int t = threadIdx.x;
        int c0 = 32 * (t & 3) + (t >> 2);       // true col of position 2t; pair col = c0+16
        int cur = sg[0];
        float2 m = sv[0][t];
        for (int ww = 1; ww < 16; ++ww) {
            int gg = sg[ww];
            float2 vv = sv[ww][t];
            if (gg == cur) { m.x = fmaxf(m.x, vv.x); m.y = fmaxf(m.y, vv.y); }
            else {
                atomicMax(&pool[cur * 128 + c0], __float_as_int(m.x));
                atomicMax(&pool[cur * 128 + c0 + 16], __float_as_int(m.y));
                cur = gg; m = vv;
            }
        }
        atomicMax(&pool[cur * 128 + c0], __float_as_int(m.x));
        atomicMax(&pool[cur * 128 + c0 + 16], __float_as_int(m.y));
    }
}

// ---------------------------------------------------------------- final MLP + log_softmax, 1 block/graph
__global__ __launch_bounds__(128) void k_mlp(const float* __restrict__ pool, const float* __restrict__ W0,
                                             const float* __restrict__ b0, const float* __restrict__ W1,
                                             const float* __restrict__ b1, float* __restrict__ out) {
    __shared__ float rowv[128];
    __shared__ float h2[128];
    __shared__ float ps[80];
    __shared__ float h3[10];
    __shared__ float lsed;
    int g = blockIdx.x, t = threadIdx.x;
    rowv[t] = pool[g * 128 + t];
    __syncthreads();
    float acc = b0[t];
    for (int k = 0; k < 128; ++k) acc = fmaf(rowv[k], W0[k * 128 + t], acc);
    h2[t] = fmaxf(acc, 0.f);
    __syncthreads();
    if (t < 80) {                               // layer 2: 10 outputs x 8 partials
        int j = t >> 3, p = t & 7;
        float a = 0.f;
        int k0 = p * 16;
        for (int k = k0; k < k0 + 16; ++k) a = fmaf(h2[k], W1[k * 10 + j], a);
        ps[t] = a;
    }
    __syncthreads();
    if (t < 10) {
        float a = b1[t];
#pragma unroll
        for (int p = 0; p < 8; ++p) a += ps[t * 8 + p];
        h3[t] = fmaxf(a, 0.f);
    }
    __syncthreads();
    if (t == 0) {
        float mx = h3[0];
        for (int j = 1; j < 10; ++j) mx = fmaxf(mx, h3[j]);
        float s = 0.f;
        for (int j = 0; j < 10; ++j) s += expf(h3[j] - mx);
        lsed = logf(s) + mx;
    }
    __syncthreads();
    if (t < 10) out[g * 10 + t] = h3[t] - lsed;
}

// ----------------------------------------------------------------
extern "C" void kernel_launch(void* const* d_in, const int* in_sizes, int n_in,
                              void* d_out, int out_size, void* d_ws, size_t ws_size,
                              hipStream_t stream) {
    const float* x   = (const float*)d_in[0];
    const int* eidx  = (const int*)d_in[1];
    const int* batch = (const int*)d_in[2];
    const float* w0  = (const float*)d_in[3];
    const float* b0  = (const float*)d_in[4];
    const float* w1  = (const float*)d_in[5];
    const float* b1  = (const float*)d_in[6];
    const float* lw0 = (const float*)d_in[7];
    const float* lb0 = (const float*)d_in[8];
    const float* lw1 = (const float*)d_in[9];
    const float* lb1 = (const float*)d_in[10];
    float* out = (float*)d_out;

    int n = in_sizes[2];
    int E = in_sizes[1] / 2;
    const int* row = eidx;        // sources
    const int* col = eidx + E;    // destinations
    int nbins = (n + 255) >> 8;   // 196 (n < 2^16 required for packing)
    int nb1 = (E + 4095) / 4096;

    char* ws = (char*)d_ws;
    size_t o = 0;
    auto take = [&](size_t bytes) { void* p = ws + o; o += (bytes + 255) & ~(size_t)255; return p; };
    int*      binCur   = (int*)     take(256 * 4);
    int*      off_     = (int*)     take((size_t)n * 4);
    int*      end_     = (int*)     take((size_t)n * 4);
    float*    dinv     = (float*)   take((size_t)n * 4);
    int*      csrA     = (int*)     take(((size_t)nbins * BINCAP + 128) * 4);
    int*      csr      = csrA + 64;                                  // 64-slot front pad
    unsigned* ebuf     = (unsigned*)take(((size_t)nbins * BINCAP + 64) * 4);
    uint4*    Wp0      = (uint4*)   take(2048 * 16);
    uint4*    Wp1      = (uint4*)   take(2048 * 16);
    float*    b0p      = (float*)   take(128 * 4);
    float*    b1p      = (float*)   take(128 * 4);
    uint2*    rows0    = (uint2*)   take((size_t)(n + 1) * 128);     // int8 rows + zero row
    float*    scl0     = (float*)   take((size_t)(n + 1) * 4);
    uint2*    rows1    = (uint2*)   take((size_t)(n + 1) * 128);
    float*    scl1     = (float*)   take((size_t)(n + 1) * 4);
    int*      pool     = (int*)     take(64 * 128 * 4);

    k_initW<<<8, 256, 0, stream>>>(w0, w1, b0, b1, Wp0, Wp1, b0p, b1p, binCur, pool,
                                   rows0, scl0, rows1, scl1, nbins, n);
    k_p1scatter<<<nb1, 256, 0, stream>>>(row, col, binCur, ebuf, E);
    k_p2sort<<<nbins, 256, 0, stream>>>(ebuf, binCur, csr, off_, end_, dinv, n);

    int mtBlocks = ((n + 15) / 16 + 3) / 4;

    k_gemm0<<<mtBlocks, 256, 0, stream>>>(x, Wp0, dinv, rows0, scl0, n);
    k_aggemm<<<n / 16, 256, 0, stream>>>(rows0, scl0, off_, end_, csr, dinv, b0p, Wp1, rows1, scl1, n);
    k_agg1<<<n / 16, 256, 0, stream>>>(rows1, scl1, off_, end_, csr, dinv, b1p, batch, pool, n);
    k_mlp<<<64, 128, 0, stream>>>((const float*)pool, lw0, lb0, lw1, lb1, out);
}